// Round 5
// baseline (1021.869 us; speedup 1.0000x reference)
//
#include <hip/hip_runtime.h>
#include <cstdint>

typedef __bf16 bf16;
typedef __bf16 bf16x8 __attribute__((ext_vector_type(8)));
typedef float f32x4 __attribute__((ext_vector_type(4)));

#define DEVI __device__ __forceinline__

DEVI float bits2f(uint32_t u){ union{uint32_t u;float f;}x; x.u=u; return x.f; }

DEVI void gload_lds16(const void* g, void* l){
  __builtin_amdgcn_global_load_lds(
    (const __attribute__((address_space(1))) uint32_t*)g,
    (__attribute__((address_space(3))) uint32_t*)l, 16, 0, 0);
}

// ---------- cast fp32 -> bf16, 8 elems/thread ----------
__global__ __launch_bounds__(256) void k_cast(const float* __restrict__ x, bf16* __restrict__ o, int n){
  int i = (blockIdx.x*256 + threadIdx.x)*8;
  if (i >= n) return;
  float4 a = *(const float4*)(x+i);
  float4 b = *(const float4*)(x+i+4);
  union { bf16 h[8]; uint4 u; } r;
  r.h[0]=(bf16)a.x; r.h[1]=(bf16)a.y; r.h[2]=(bf16)a.z; r.h[3]=(bf16)a.w;
  r.h[4]=(bf16)b.x; r.h[5]=(bf16)b.y; r.h[6]=(bf16)b.z; r.h[7]=(bf16)b.w;
  *(uint4*)(o+i) = r.u;
}

// ---------- transpose + cast: WT[c][r] = W[r][c] ----------
__global__ __launch_bounds__(256) void k_transpose(const float* __restrict__ W, bf16* __restrict__ WT, int R, int Ccols){
  __shared__ float tile[32][33];
  int bc = blockIdx.x*32, br = blockIdx.y*32;
  int lc = threadIdx.x & 31, lr = threadIdx.x >> 5; // lr 0..7
  #pragma unroll
  for (int i=0;i<4;i++){
    int r = lr + i*8;
    tile[r][lc] = W[(size_t)(br+r)*Ccols + bc + lc];
  }
  __syncthreads();
  #pragma unroll
  for (int i=0;i<4;i++){
    int r = lr + i*8;
    WT[(size_t)(bc+r)*R + br + lc] = (bf16)tile[lc][r];
  }
}

// =====================================================================
// r3 structure (256x256, BK=64, 8-wave, pipelined ds_reads) with MODE
// ablation (m233-style decomposition):
//   MODE 0: full (real output; launched LAST so its data wins)
//   MODE 1: no stage/vmcnt in K-loop (ds_reads + barriers + MFMA)
//   MODE 2: no ds_reads in K-loop (stage + vmcnt + barriers + MFMA)
//   MODE 3: barriers + MFMA only
// Probe outputs are garbage but are fully overwritten by the MODE-0
// dispatch that follows; timing is data-independent -> deterministic.
// =====================================================================
template<int EPI, int MODE>
__global__ __launch_bounds__(512, 2) void k_gemm(
    const bf16* __restrict__ A, const bf16* __restrict__ BT, bf16* __restrict__ C,
    int M, int N, int K,
    const float* __restrict__ bias, const float* __restrict__ resid)
{
  __shared__ __align__(16) bf16 lds[2][2][256*64];   // [slot][0=A,1=B] = 128 KiB
  bf16* bA0 = &lds[0][0][0]; bf16* bB0 = &lds[0][1][0];
  bf16* bA1 = &lds[1][0][0]; bf16* bB1 = &lds[1][1][0];

  const int t = threadIdx.x, w = t>>6, l = t&63;
  const int wm = w>>2, wn = w&3;

  // XCD-aware bijective block swizzle (m204 variant)
  const int nwg = gridDim.x * gridDim.y;
  const int orig = blockIdx.y * gridDim.x + blockIdx.x;
  const int q = nwg >> 3, r = nwg & 7;
  const int xcd = orig & 7, loc = orig >> 3;
  const int swz = (xcd < r ? xcd*(q+1) : r*(q+1) + (xcd-r)*q) + loc;
  const int bx = swz % gridDim.x, by = swz / gridDim.x;
  const int bm = by*256, bn = bx*256;

  // swizzled read column offsets (bytes within a 128B row), kk = 0,1
  const int co0 = (16*(l>>4)) ^ ((l&7)<<4);
  const int co1 = (64 + 16*(l>>4)) ^ ((l&7)<<4);

  // A staging: wave stages its OWN 32 rows [wm*128+wn*32, +32), 4 issues of 8 rows.
  auto stageA = [&](const bf16* G, bf16* Ldst, int j, int k0){
    int row = wm*128 + wn*32 + j*8 + (l>>3);
    int col = 8*((l&7) ^ (l>>3));
    gload_lds16(G + (size_t)(bm + row)*K + k0 + col,
                Ldst + (wm*128 + wn*32 + j*8)*64);
  };
  // B staging: cooperative, issue j covers rows j*64 + w*8 .. +8.
  auto stageB = [&](const bf16* G, bf16* Ldst, int j, int k0){
    int row = j*64 + w*8 + (l>>3);
    int col = 8*((l&7) ^ (l>>3));
    gload_lds16(G + (size_t)(bn + row)*K + k0 + col,
                Ldst + (j*64 + w*8)*64);
  };

#define RD_AA(dst, qd, base) {                                                  \
    const int r0 = wm*128 + (qd)*32 + (l&15);                                   \
    dst[0][0] = *(const bf16x8*)((const char*)(base) + (r0   )*128 + co0);      \
    dst[0][1] = *(const bf16x8*)((const char*)(base) + (r0   )*128 + co1);      \
    dst[1][0] = *(const bf16x8*)((const char*)(base) + (r0+16)*128 + co0);      \
    dst[1][1] = *(const bf16x8*)((const char*)(base) + (r0+16)*128 + co1);      \
  }

#define MFMA_Q(P, AA) {                                                         \
    __builtin_amdgcn_s_setprio(1);                                              \
    _Pragma("unroll")                                                           \
    for (int kk=0;kk<2;++kk)                                                    \
      _Pragma("unroll")                                                         \
      for (int i=0;i<2;++i)                                                     \
        _Pragma("unroll")                                                       \
        for (int nf=0;nf<4;++nf)                                                \
          acc[2*(P)+i][nf] = __builtin_amdgcn_mfma_f32_16x16x32_bf16(           \
              AA[i][kk], bfr[nf][kk], acc[2*(P)+i][nf], 0,0,0);                 \
    __builtin_amdgcn_s_setprio(0);                                              \
  }

#define BAR asm volatile("s_barrier" ::: "memory")

  constexpr bool DO_VM = (MODE==0 || MODE==2);   // stage + vmcnt
  constexpr bool DO_DS = (MODE==0 || MODE==1);   // ds_read fragments

  f32x4 acc[8][4] = {};
  const int NT = K >> 6;

  // ---- prologue (identical for all modes): stage A(0), B(0), B(1) ----
  #pragma unroll
  for (int j=0;j<4;++j) stageA(A, bA0, j, 0);
  #pragma unroll
  for (int j=0;j<4;++j) stageB(BT, bB0, j, 0);
  __builtin_amdgcn_sched_barrier(0);
  if (NT > 1){
    #pragma unroll
    for (int j=0;j<4;++j) stageB(BT, bB1, j, 64);
    asm volatile("s_waitcnt vmcnt(4)" ::: "memory");
  } else {
    asm volatile("s_waitcnt vmcnt(0)" ::: "memory");
  }
  BAR;

  bf16x8 aaA[2][2], aaB[2][2];
  bf16x8 bfr[4][2];
  if (DO_DS){
    RD_AA(aaA, wn, bA0);   // tile-0 first quadrant (own rows, own-staged)
  } else {
    // one-time frag init from staged LDS (data-independent timing; keeps
    // MFMA operands live without per-phase LDS traffic)
    #pragma unroll
    for (int i=0;i<2;++i)
      #pragma unroll
      for (int k2=0;k2<2;++k2){
        aaA[i][k2] = *(const bf16x8*)(bA0 + (i*2+k2)*8 + l*8);
        aaB[i][k2] = *(const bf16x8*)(bA0 + 512 + (i*2+k2)*8 + l*8);
      }
    #pragma unroll
    for (int nf=0;nf<4;++nf)
      #pragma unroll
      for (int k2=0;k2<2;++k2)
        bfr[nf][k2] = *(const bf16x8*)(bB0 + (nf*2+k2)*8 + l*8);
  }

  for (int T = 0; T < NT; ++T){
    bf16* sA  = (T&1) ? bA1 : bA0;
    bf16* sB  = (T&1) ? bB1 : bB0;
    bf16* sAn = (T&1) ? bA0 : bA1;
    const int kA = (T+1)<<6, kB = (T+2)<<6;
    const bool stA = (T+1) < NT, stB = (T+2) < NT;

    // B fragments for the whole K-tile, register-cached (8 x ds_read_b128)
    if (DO_DS){
      const int rb = wn*64 + (l&15);
      #pragma unroll
      for (int nf=0;nf<4;++nf){
        bfr[nf][0] = *(const bf16x8*)((const char*)sB + (rb+nf*16)*128 + co0);
        bfr[nf][1] = *(const bf16x8*)((const char*)sB + (rb+nf*16)*128 + co1);
      }
    }

    // P0: compute quad (wn+0), read quad (wn+1), stage A(T+1) j=0,1
    if (DO_DS) RD_AA(aaB, (wn+1)&3, sA);
    if (DO_VM && stA){ stageA(A, sAn, 0, kA); stageA(A, sAn, 1, kA); }
    BAR; MFMA_Q(0, aaA); BAR;

    // P1: compute quad (wn+1), read quad (wn+2), stage A(T+1) j=2,3
    if (DO_DS) RD_AA(aaA, (wn+2)&3, sA);
    if (DO_VM && stA){ stageA(A, sAn, 2, kA); stageA(A, sAn, 3, kA); }
    BAR; MFMA_Q(1, aaB); BAR;

    // P2: compute quad (wn+2), read quad (wn+3), stage B(T+2) j=0,1
    if (DO_DS) RD_AA(aaB, (wn+3)&3, sA);
    if (DO_VM && stB){ stageB(BT, sB, 0, kB); stageB(BT, sB, 1, kB); }
    BAR; MFMA_Q(2, aaA); BAR;

    // P3: compute quad (wn+3); stage B(T+2) j=2,3; vmcnt; prefetch next tile's
    // quad wn from sAn (own rows, confirmed by own vmcnt).
    if (DO_VM){
      if (stB){
        stageB(BT, sB, 2, kB); stageB(BT, sB, 3, kB);
        asm volatile("s_waitcnt vmcnt(4)" ::: "memory");
      } else {
        asm volatile("s_waitcnt vmcnt(0)" ::: "memory");
      }
    }
    if (DO_DS && stA) RD_AA(aaA, wn, sAn);
    BAR; MFMA_Q(3, aaB); BAR;
  }
#undef RD_AA
#undef MFMA_Q
#undef BAR

  // ---- epilogue ----
  #pragma unroll
  for (int P=0; P<4; ++P){
    const int qd = (P+wn)&3;
    #pragma unroll
    for (int i=0;i<2;++i){
      #pragma unroll
      for (int nf=0; nf<4; ++nf){
        #pragma unroll
        for (int r2=0; r2<4; ++r2){
          int row = bm + wm*128 + qd*32 + i*16 + (l>>4)*4 + r2;
          int col = bn + wn*64 + nf*16 + (l&15);
          float v = acc[2*P+i][nf][r2];
          if (EPI==1) v += bias[col] + resid[(size_t)row*N + col];
          C[(size_t)row*N + col] = (bf16)v;
        }
      }
    }
  }
}

// ---------- channel scores: Sp[ks][bg][d][e] = sum_{n in ks-chunk} k[n][d]*v[n][e] ----------
__global__ __launch_bounds__(256) void k_scores(const bf16* __restrict__ qkv, float* __restrict__ Sp){
  const int ks = blockIdx.x, bg = blockIdx.y;
  const int b = bg>>4, g = bg&15;
  __shared__ __align__(16) bf16 kT[64][64];
  __shared__ __align__(16) bf16 vT[64][64];
  const int t = threadIdx.x;
  const int d0 = (t&15)*4, e0 = (t>>4)*4;
  float acc[4][4] = {};
  const bf16* base = qkv + (size_t)(b*4096 + ks*512)*3072 + g*64;
  for (int sub=0; sub<8; ++sub){
    __syncthreads();
    for (int idx=t; idx<512; idx+=256){
      int row = idx>>3, c8 = (idx&7)*8;
      const bf16* s = base + (size_t)(sub*64+row)*3072 + 1024 + c8;
      *(uint4*)&kT[row][c8] = *(const uint4*)s;
      *(uint4*)&vT[row][c8] = *(const uint4*)(s + 1024);
    }
    __syncthreads();
    #pragma unroll 4
    for (int n=0;n<64;++n){
      uint2 ku = *(const uint2*)&kT[n][d0];
      uint2 vu = *(const uint2*)&vT[n][e0];
      float kf[4] = { bits2f(ku.x<<16), bits2f(ku.x&0xffff0000u), bits2f(ku.y<<16), bits2f(ku.y&0xffff0000u) };
      float vf[4] = { bits2f(vu.x<<16), bits2f(vu.x&0xffff0000u), bits2f(vu.y<<16), bits2f(vu.y&0xffff0000u) };
      #pragma unroll
      for (int i=0;i<4;++i)
        #pragma unroll
        for (int j=0;j<4;++j)
          acc[i][j] += kf[i]*vf[j];
    }
  }
  float* o = Sp + ((size_t)ks*128 + bg)*4096;
  #pragma unroll
  for (int i=0;i<4;++i)
    #pragma unroll
    for (int j=0;j<4;++j)
      o[(d0+i)*64 + e0+j] = acc[i][j];
}

// ---------- reduce partials, scale, softmax over e, write bf16 P ----------
__global__ __launch_bounds__(256) void k_softmax(const float* __restrict__ Sp, bf16* __restrict__ P){
  const int bg = blockIdx.x;
  __shared__ float S[64][64];
  const int t = threadIdx.x;
  for (int idx=t; idx<4096; idx+=256){
    float s = 0;
    #pragma unroll
    for (int ks=0;ks<8;++ks) s += Sp[((size_t)ks*128+bg)*4096 + idx];
    S[idx>>6][idx&63] = s * 0.125f;  // scale = hd^-0.5
  }
  __syncthreads();
  const int row = t>>2, qd = t&3;
  float m = -3.4e38f;
  #pragma unroll
  for (int j=0;j<16;++j) m = fmaxf(m, S[row][qd*16+j]);
  m = fmaxf(m, __shfl_xor(m,1));
  m = fmaxf(m, __shfl_xor(m,2));
  float e[16]; float sum = 0.f;
  #pragma unroll
  for (int j=0;j<16;++j){ e[j] = expf(S[row][qd*16+j]-m); sum += e[j]; }
  sum += __shfl_xor(sum,1);
  sum += __shfl_xor(sum,2);
  float inv = 1.0f/sum;
  #pragma unroll
  for (int j=0;j<16;++j) P[(size_t)bg*4096 + row*64 + qd*16 + j] = (bf16)(e[j]*inv);
}

// ---------- out2[n][d] = sum_e P[d][e] * q[n][e], per (b,g); MFMA ----------
__global__ __launch_bounds__(256) void k_apply(const bf16* __restrict__ qkv, const bf16* __restrict__ P, bf16* __restrict__ outA){
  const int bg = blockIdx.y, b = bg>>4, g = bg&15;
  const int m0 = blockIdx.x*128;
  __shared__ __align__(16) bf16 Pl[64][72];   // pad 64->72 elems (144B rows, 16B-aligned)
  const int t = threadIdx.x, w = t>>6, l = t&63;
  for (int idx=t; idx<1024; idx+=256){
    int r = idx>>4, c4 = (idx&15)*4;
    *(uint2*)&Pl[r][c4] = *(const uint2*)&P[(size_t)bg*4096 + r*64 + c4];
  }
  __syncthreads();
  f32x4 acc[2][4] = {};
  const bf16* qb = qkv + (size_t)(b*4096 + m0 + w*32)*3072 + g*64;
  #pragma unroll
  for (int kk=0; kk<64; kk+=32){
    bf16x8 af[2], pf[4];
    #pragma unroll
    for (int mf=0;mf<2;++mf)
      af[mf] = *(const bf16x8*)(qb + (size_t)(mf*16 + (l&15))*3072 + kk + 8*(l>>4));
    #pragma unroll
    for (int nf=0;nf<4;++nf)
      pf[nf] = *(const bf16x8*)&Pl[nf*16 + (l&15)][kk + 8*(l>>4)];
    #pragma unroll
    for (int mf=0;mf<2;++mf)
      #pragma unroll
      for (int nf=0;nf<4;++nf)
        acc[mf][nf] = __builtin_amdgcn_mfma_f32_16x16x32_bf16(af[mf], pf[nf], acc[mf][nf], 0,0,0);
  }
  #pragma unroll
  for (int mf=0;mf<2;++mf)
    #pragma unroll
    for (int nf=0;nf<4;++nf)
      #pragma unroll
      for (int r=0;r<4;++r){
        int rown = m0 + w*32 + mf*16 + (l>>4)*4 + r;
        int col = g*64 + nf*16 + (l&15);
        outA[(size_t)(b*4096 + rown)*1024 + col] = (bf16)acc[mf][nf][r];
      }
}

// ---------- LayerNorm: wave per row of 1024 ----------
__global__ __launch_bounds__(256) void k_ln(const bf16* __restrict__ h, const float* __restrict__ gamma,
                                            const float* __restrict__ beta, float* __restrict__ y){
  const int w = threadIdx.x>>6, l = threadIdx.x&63;
  const size_t row = (size_t)blockIdx.x*4 + w;
  const bf16* hr = h + row*1024 + l*16;
  uint4 p0 = *(const uint4*)hr;
  uint4 p1 = *(const uint4*)(hr+8);
  float v[16];
  const uint32_t* pw = (const uint32_t*)&p0;
  #pragma unroll
  for (int i=0;i<4;++i){ v[2*i] = bits2f(pw[i]<<16); v[2*i+1] = bits2f(pw[i]&0xffff0000u); }
  const uint32_t* pw1 = (const uint32_t*)&p1;
  #pragma unroll
  for (int i=0;i<4;++i){ v[8+2*i] = bits2f(pw1[i]<<16); v[8+2*i+1] = bits2f(pw1[i]&0xffff0000u); }
  float s=0.f, s2=0.f;
  #pragma unroll
  for (int i=0;i<16;++i){ s+=v[i]; s2+=v[i]*v[i]; }
  #pragma unroll
  for (int off=1; off<64; off<<=1){ s += __shfl_xor(s,off); s2 += __shfl_xor(s2,off); }
  float mu = s*(1.0f/1024.0f);
  float var = s2*(1.0f/1024.0f) - mu*mu;
  float rinv = rsqrtf(var + 1e-5f);
  const float* gp = gamma + l*16; const float* bp = beta + l*16;
  float o[16];
  #pragma unroll
  for (int i=0;i<16;++i) o[i] = gp[i]*(v[i]-mu)*rinv + bp[i];
  float* yr = y + row*1024 + l*16;
  #pragma unroll
  for (int i=0;i<4;++i) ((float4*)yr)[i] = *(float4*)&o[4*i];
}

extern "C" void kernel_launch(void* const* d_in, const int* in_sizes, int n_in,
                              void* d_out, int out_size, void* d_ws, size_t ws_size,
                              hipStream_t stream){
  const float* x     = (const float*)d_in[0];
  const float* Wqkv  = (const float*)d_in[1];
  const float* Wproj = (const float*)d_in[2];
  const float* bproj = (const float*)d_in[3];
  const float* gamma = (const float*)d_in[4];
  const float* beta  = (const float*)d_in[5];
  float* y = (float*)d_out;

  char* ws = (char*)d_ws;
  size_t off = 0;
  auto alloc = [&](size_t bytes)->void*{ void* p = ws + off; off += (bytes + 255) & ~(size_t)255; return p; };
  bf16*  qkv    = (bf16*) alloc((size_t)32768*3072*2);  // 201.3 MB
  bf16*  xb     = (bf16*) alloc((size_t)32768*1024*2);  // 67.1 MB (x_bf16, then out_attn)
  bf16*  WqkvT  = (bf16*) alloc((size_t)3072*1024*2);
  bf16*  WprojT = (bf16*) alloc((size_t)1024*1024*2);
  float* Sp     = (float*)alloc((size_t)8*128*4096*4);  // 16.8 MB
  bf16*  P      = (bf16*) alloc((size_t)128*4096*2);
  bf16*  h      = qkv;  // qkv dead after k_apply; reuse for h

  k_cast<<<16384,256,0,stream>>>(x, xb, 33554432);
  k_transpose<<<dim3(96,32),256,0,stream>>>(Wqkv, WqkvT, 1024, 3072);
  k_transpose<<<dim3(32,32),256,0,stream>>>(Wproj, WprojT, 1024, 1024);

  // ---- ABLATION PROBES (garbage output; overwritten by the real GEMM1 below) ----
  // MODE 3: barriers+MFMA only | MODE 2: +stage/vmcnt | MODE 1: +ds_reads
  k_gemm<0,3><<<dim3(12,128),512,0,stream>>>(xb, WqkvT, qkv, 32768, 3072, 1024, nullptr, nullptr);
  k_gemm<0,2><<<dim3(12,128),512,0,stream>>>(xb, WqkvT, qkv, 32768, 3072, 1024, nullptr, nullptr);
  k_gemm<0,1><<<dim3(12,128),512,0,stream>>>(xb, WqkvT, qkv, 32768, 3072, 1024, nullptr, nullptr);

  // qkv = x @ Wqkv   [32768 x 3072]  (real)
  k_gemm<0,0><<<dim3(12,128),512,0,stream>>>(xb, WqkvT, qkv, 32768, 3072, 1024, nullptr, nullptr);
  // S partials (split-K over n)
  k_scores<<<dim3(8,128),256,0,stream>>>(qkv, Sp);
  k_softmax<<<128,256,0,stream>>>(Sp, P);
  // out_attn = q @ P^T  -> xb
  k_apply<<<dim3(32,128),256,0,stream>>>(qkv, P, xb);
  // h = out_attn @ Wproj + bproj + x   [32768 x 1024] bf16
  k_gemm<1,0><<<dim3(4,128),512,0,stream>>>(xb, WprojT, h, 32768, 1024, 1024, bproj, x);
  k_ln<<<8192,256,0,stream>>>(h, gamma, beta, y);
}

// Round 6
// 402.672 us; speedup vs baseline: 2.5377x; 2.5377x over previous
//
#include <hip/hip_runtime.h>
#include <cstdint>

typedef __bf16 bf16;
typedef __bf16 bf16x8 __attribute__((ext_vector_type(8)));
typedef float f32x4 __attribute__((ext_vector_type(4)));

#define DEVI __device__ __forceinline__

DEVI float bits2f(uint32_t u){ union{uint32_t u;float f;}x; x.u=u; return x.f; }

DEVI void gload_lds16(const void* g, void* l){
  __builtin_amdgcn_global_load_lds(
    (const __attribute__((address_space(1))) uint32_t*)g,
    (__attribute__((address_space(3))) uint32_t*)l, 16, 0, 0);
}

// ---------- cast fp32 -> bf16, 8 elems/thread ----------
__global__ __launch_bounds__(256) void k_cast(const float* __restrict__ x, bf16* __restrict__ o, int n){
  int i = (blockIdx.x*256 + threadIdx.x)*8;
  if (i >= n) return;
  float4 a = *(const float4*)(x+i);
  float4 b = *(const float4*)(x+i+4);
  union { bf16 h[8]; uint4 u; } r;
  r.h[0]=(bf16)a.x; r.h[1]=(bf16)a.y; r.h[2]=(bf16)a.z; r.h[3]=(bf16)a.w;
  r.h[4]=(bf16)b.x; r.h[5]=(bf16)b.y; r.h[6]=(bf16)b.z; r.h[7]=(bf16)b.w;
  *(uint4*)(o+i) = r.u;
}

// ---------- transpose + cast: WT[c][r] = W[r][c], optional batch z ----------
__global__ __launch_bounds__(256) void k_transpose(const float* __restrict__ W, bf16* __restrict__ WT,
                                                   int R, int Ccols, size_t Ws, size_t Ts){
  W += blockIdx.z*Ws; WT += blockIdx.z*Ts;
  __shared__ float tile[32][33];
  int bc = blockIdx.x*32, br = blockIdx.y*32;
  int lc = threadIdx.x & 31, lr = threadIdx.x >> 5; // lr 0..7
  #pragma unroll
  for (int i=0;i<4;i++){
    int r = lr + i*8;
    tile[r][lc] = W[(size_t)(br+r)*Ccols + bc + lc];
  }
  __syncthreads();
  #pragma unroll
  for (int i=0;i<4;i++){
    int r = lr + i*8;
    WT[(size_t)(bc+r)*R + br + lc] = (bf16)tile[lc][r];
  }
}

// =====================================================================
// 128x128-tile bf16 GEMM (r1 structure, verified 841 TF), batched via z.
// C[m][n] = sum_k A[m][k] * BT[n][k].  lda/ldb decoupled from K.
// =====================================================================
__global__ __launch_bounds__(256) void k_gemm128(
    const bf16* __restrict__ A, const bf16* __restrict__ BT, bf16* __restrict__ C,
    int N, int K, int lda, int ldb,
    size_t As, size_t Bs, size_t Cs)
{
  A += blockIdx.z*As; BT += blockIdx.z*Bs; C += blockIdx.z*Cs;
  __shared__ __align__(16) bf16 sA[128*64];
  __shared__ __align__(16) bf16 sB[128*64];
  const int t = threadIdx.x, w = t>>6, l = t&63;
  const int bm = blockIdx.y*128, bn = blockIdx.x*128;
  const int wr = (w>>1)*64, wc = (w&1)*64;
  f32x4 acc[4][4] = {};
  const int srow = l>>3;                      // row within chunk (0..7) == row&7
  const int scol = ((l&7) ^ (l>>3))*8;        // swizzled source col (elements)
  const int nk = K>>6;
  for (int kt=0; kt<nk; ++kt) {
    const int k0 = kt*64;
    #pragma unroll
    for (int i=0;i<4;++i){
      int c = w*4+i;
      int row = c*8 + srow;
      gload_lds16(A  + (size_t)(bm+row)*lda + k0 + scol, (char*)sA + c*1024);
      gload_lds16(BT + (size_t)(bn+row)*ldb + k0 + scol, (char*)sB + c*1024);
    }
    __syncthreads();
    #pragma unroll
    for (int kk=0; kk<64; kk+=32) {
      bf16x8 af[4], bfr[4];
      const int xr = ((kk + 8*(l>>4))*2) ^ ((l&7)<<4);
      #pragma unroll
      for (int mf=0;mf<4;++mf){
        int row = wr + mf*16 + (l&15);
        af[mf] = *(const bf16x8*)((const char*)sA + row*128 + xr);
      }
      #pragma unroll
      for (int nf=0;nf<4;++nf){
        int row = wc + nf*16 + (l&15);
        bfr[nf] = *(const bf16x8*)((const char*)sB + row*128 + xr);
      }
      #pragma unroll
      for (int mf=0;mf<4;++mf)
        #pragma unroll
        for (int nf=0;nf<4;++nf)
          acc[mf][nf] = __builtin_amdgcn_mfma_f32_16x16x32_bf16(af[mf], bfr[nf], acc[mf][nf], 0,0,0);
    }
    __syncthreads();
  }
  #pragma unroll
  for (int mf=0;mf<4;++mf)
    #pragma unroll
    for (int nf=0;nf<4;++nf)
      #pragma unroll
      for (int r=0;r<4;++r){
        int row = bm + wr + mf*16 + (l>>4)*4 + r;
        int col = bn + wc + nf*16 + (l&15);
        C[(size_t)row*N + col] = (bf16)acc[mf][nf][r];
      }
}

// =====================================================================
// 256x256-tile pipelined GEMM (r3 structure) with fused epilogue:
// C = bf16(A*BT^T + bias + resid), batched via z.
// =====================================================================
__global__ __launch_bounds__(512, 2) void k_gemm256(
    const bf16* __restrict__ A, const bf16* __restrict__ BT, bf16* __restrict__ C,
    int N, int K,
    const float* __restrict__ bias, const float* __restrict__ resid,
    size_t As, size_t Bs, size_t Cs, size_t Rs)
{
  A += blockIdx.z*As; BT += blockIdx.z*Bs; C += blockIdx.z*Cs; resid += blockIdx.z*Rs;
  __shared__ __align__(16) bf16 lds[2][2][256*64];   // 128 KiB
  bf16* bA0 = &lds[0][0][0]; bf16* bB0 = &lds[0][1][0];
  bf16* bA1 = &lds[1][0][0]; bf16* bB1 = &lds[1][1][0];

  const int t = threadIdx.x, w = t>>6, l = t&63;
  const int wm = w>>2, wn = w&3;

  const int nwg = gridDim.x * gridDim.y;
  const int orig = blockIdx.y * gridDim.x + blockIdx.x;
  const int q = nwg >> 3, r = nwg & 7;
  const int xcd = orig & 7, loc = orig >> 3;
  const int swz = (xcd < r ? xcd*(q+1) : r*(q+1) + (xcd-r)*q) + loc;
  const int bx = swz % gridDim.x, by = swz / gridDim.x;
  const int bm = by*256, bn = bx*256;

  const int co0 = (16*(l>>4)) ^ ((l&7)<<4);
  const int co1 = (64 + 16*(l>>4)) ^ ((l&7)<<4);

  auto stageA = [&](const bf16* G, bf16* Ldst, int j, int k0){
    int row = wm*128 + wn*32 + j*8 + (l>>3);
    int col = 8*((l&7) ^ (l>>3));
    gload_lds16(G + (size_t)(bm + row)*K + k0 + col,
                Ldst + (wm*128 + wn*32 + j*8)*64);
  };
  auto stageB = [&](const bf16* G, bf16* Ldst, int j, int k0){
    int row = j*64 + w*8 + (l>>3);
    int col = 8*((l&7) ^ (l>>3));
    gload_lds16(G + (size_t)(bn + row)*K + k0 + col,
                Ldst + (j*64 + w*8)*64);
  };

#define RD_AA(dst, qd, base) {                                                  \
    const int r0 = wm*128 + (qd)*32 + (l&15);                                   \
    dst[0][0] = *(const bf16x8*)((const char*)(base) + (r0   )*128 + co0);      \
    dst[0][1] = *(const bf16x8*)((const char*)(base) + (r0   )*128 + co1);      \
    dst[1][0] = *(const bf16x8*)((const char*)(base) + (r0+16)*128 + co0);      \
    dst[1][1] = *(const bf16x8*)((const char*)(base) + (r0+16)*128 + co1);      \
  }

#define MFMA_Q(P, AA) {                                                         \
    __builtin_amdgcn_s_setprio(1);                                              \
    _Pragma("unroll")                                                           \
    for (int kk=0;kk<2;++kk)                                                    \
      _Pragma("unroll")                                                         \
      for (int i=0;i<2;++i)                                                     \
        _Pragma("unroll")                                                       \
        for (int nf=0;nf<4;++nf)                                                \
          acc[2*(P)+i][nf] = __builtin_amdgcn_mfma_f32_16x16x32_bf16(           \
              AA[i][kk], bfr[nf][kk], acc[2*(P)+i][nf], 0,0,0);                 \
    __builtin_amdgcn_s_setprio(0);                                              \
  }

#define BAR asm volatile("s_barrier" ::: "memory")

  f32x4 acc[8][4] = {};
  const int NT = K >> 6;

  #pragma unroll
  for (int j=0;j<4;++j) stageA(A, bA0, j, 0);
  #pragma unroll
  for (int j=0;j<4;++j) stageB(BT, bB0, j, 0);
  __builtin_amdgcn_sched_barrier(0);
  if (NT > 1){
    #pragma unroll
    for (int j=0;j<4;++j) stageB(BT, bB1, j, 64);
    asm volatile("s_waitcnt vmcnt(4)" ::: "memory");
  } else {
    asm volatile("s_waitcnt vmcnt(0)" ::: "memory");
  }
  BAR;

  bf16x8 aaA[2][2], aaB[2][2];
  RD_AA(aaA, wn, bA0);

  for (int T = 0; T < NT; ++T){
    bf16* sA  = (T&1) ? bA1 : bA0;
    bf16* sB  = (T&1) ? bB1 : bB0;
    bf16* sAn = (T&1) ? bA0 : bA1;
    const int kA = (T+1)<<6, kB = (T+2)<<6;
    const bool stA = (T+1) < NT, stB = (T+2) < NT;

    bf16x8 bfr[4][2];
    const int rb = wn*64 + (l&15);
    #pragma unroll
    for (int nf=0;nf<4;++nf){
      bfr[nf][0] = *(const bf16x8*)((const char*)sB + (rb+nf*16)*128 + co0);
      bfr[nf][1] = *(const bf16x8*)((const char*)sB + (rb+nf*16)*128 + co1);
    }

    RD_AA(aaB, (wn+1)&3, sA);
    if (stA){ stageA(A, sAn, 0, kA); stageA(A, sAn, 1, kA); }
    BAR; MFMA_Q(0, aaA); BAR;

    RD_AA(aaA, (wn+2)&3, sA);
    if (stA){ stageA(A, sAn, 2, kA); stageA(A, sAn, 3, kA); }
    BAR; MFMA_Q(1, aaB); BAR;

    RD_AA(aaB, (wn+3)&3, sA);
    if (stB){ stageB(BT, sB, 0, kB); stageB(BT, sB, 1, kB); }
    BAR; MFMA_Q(2, aaA); BAR;

    if (stB){
      stageB(BT, sB, 2, kB); stageB(BT, sB, 3, kB);
      asm volatile("s_waitcnt vmcnt(4)" ::: "memory");
    } else {
      asm volatile("s_waitcnt vmcnt(0)" ::: "memory");
    }
    if (stA) RD_AA(aaA, wn, sAn);
    BAR; MFMA_Q(3, aaB); BAR;
  }
#undef RD_AA
#undef MFMA_Q
#undef BAR

  #pragma unroll
  for (int P=0; P<4; ++P){
    const int qd = (P+wn)&3;
    #pragma unroll
    for (int i=0;i<2;++i){
      #pragma unroll
      for (int nf=0; nf<4; ++nf){
        #pragma unroll
        for (int r2=0; r2<4; ++r2){
          int row = bm + wm*128 + qd*32 + i*16 + (l>>4)*4 + r2;
          int col = bn + wn*64 + nf*16 + (l&15);
          float v = acc[2*P+i][nf][r2] + bias[col] + resid[(size_t)row*N + col];
          C[(size_t)row*N + col] = (bf16)v;
        }
      }
    }
  }
}

// ---------- fused S = scale * T2_g @ Wv_g^T + row softmax -> Aatt[bg][64][64] ----------
__global__ __launch_bounds__(256) void k_sgemm64(const bf16* __restrict__ T2, const bf16* __restrict__ WqkvT,
                                                 bf16* __restrict__ Aatt){
  const int bg = blockIdx.x, b = bg>>4, g = bg&15;
  const bf16* Arows = T2 + (size_t)b*1048576 + (size_t)(g*64)*1024;   // [64][1024] rows d
  const bf16* Brows = WqkvT + (size_t)(2048 + g*64)*1024;             // [64][1024] rows e (Wv cols)
  __shared__ __align__(16) bf16 sA[64*64];
  __shared__ __align__(16) bf16 sB[64*64];
  const int t = threadIdx.x, w = t>>6, l = t&63;
  const int srow = l>>3, scol = ((l&7)^(l>>3))*8;
  f32x4 acc[4] = {};
  for (int kt=0; kt<16; ++kt){
    const int k0 = kt*64;
    gload_lds16(Arows + (size_t)(w*8+srow)*1024 + k0 + scol,      sA + (w*8)*64);
    gload_lds16(Arows + (size_t)(32+w*8+srow)*1024 + k0 + scol,   sA + (32+w*8)*64);
    gload_lds16(Brows + (size_t)(w*8+srow)*1024 + k0 + scol,      sB + (w*8)*64);
    gload_lds16(Brows + (size_t)(32+w*8+srow)*1024 + k0 + scol,   sB + (32+w*8)*64);
    __syncthreads();
    #pragma unroll
    for (int kk=0; kk<64; kk+=32){
      const int xr = ((kk + 8*(l>>4))*2) ^ ((l&7)<<4);
      bf16x8 af = *(const bf16x8*)((const char*)sA + (w*16+(l&15))*128 + xr);
      #pragma unroll
      for (int nf=0; nf<4; ++nf){
        bf16x8 bfv = *(const bf16x8*)((const char*)sB + (nf*16+(l&15))*128 + xr);
        acc[nf] = __builtin_amdgcn_mfma_f32_16x16x32_bf16(af, bfv, acc[nf], 0,0,0);
      }
    }
    __syncthreads();
  }
  // lane holds rows r = w*16 + (l>>4)*4 + reg, cols nf*16 + (l&15); softmax over cols
  #pragma unroll
  for (int reg=0; reg<4; ++reg){
    float m = -3.4e38f;
    #pragma unroll
    for (int nf=0; nf<4; ++nf) m = fmaxf(m, acc[nf][reg]);
    m = fmaxf(m, __shfl_xor(m,1)); m = fmaxf(m, __shfl_xor(m,2));
    m = fmaxf(m, __shfl_xor(m,4)); m = fmaxf(m, __shfl_xor(m,8));
    float e[4]; float s = 0.f;
    #pragma unroll
    for (int nf=0; nf<4; ++nf){ e[nf] = __expf((acc[nf][reg]-m)*0.125f); s += e[nf]; }
    s += __shfl_xor(s,1); s += __shfl_xor(s,2); s += __shfl_xor(s,4); s += __shfl_xor(s,8);
    const float inv = 1.0f/s;
    const int row = w*16 + (l>>4)*4 + reg;
    #pragma unroll
    for (int nf=0; nf<4; ++nf)
      Aatt[(size_t)bg*4096 + row*64 + nf*16 + (l&15)] = (bf16)(e[nf]*inv);
  }
}

// ---------- U[c][g*64+d] = sum_e Wq[c][g*64+e] * Aatt_bg[d][e] ----------
__global__ __launch_bounds__(256) void k_applyW(const bf16* __restrict__ Wqkvb, const bf16* __restrict__ Aatt,
                                                bf16* __restrict__ U){
  const int bg = blockIdx.y, b = bg>>4, g = bg&15;
  const int m0 = blockIdx.x*128;
  __shared__ __align__(16) bf16 Pl[64][72];
  const int t = threadIdx.x, w = t>>6, l = t&63;
  for (int idx=t; idx<1024; idx+=256){
    int r2 = idx>>4, c4 = (idx&15)*4;
    *(uint2*)&Pl[r2][c4] = *(const uint2*)&Aatt[(size_t)bg*4096 + r2*64 + c4];
  }
  __syncthreads();
  f32x4 acc[2][4] = {};
  const bf16* Ab = Wqkvb + (size_t)(m0 + w*32)*3072 + g*64;
  #pragma unroll
  for (int kk=0; kk<64; kk+=32){
    bf16x8 af[2], pf[4];
    #pragma unroll
    for (int mf=0;mf<2;++mf)
      af[mf] = *(const bf16x8*)(Ab + (size_t)(mf*16 + (l&15))*3072 + kk + 8*(l>>4));
    #pragma unroll
    for (int nf=0;nf<4;++nf)
      pf[nf] = *(const bf16x8*)&Pl[nf*16 + (l&15)][kk + 8*(l>>4)];
    #pragma unroll
    for (int mf=0;mf<2;++mf)
      #pragma unroll
      for (int nf=0;nf<4;++nf)
        acc[mf][nf] = __builtin_amdgcn_mfma_f32_16x16x32_bf16(af[mf], pf[nf], acc[mf][nf], 0,0,0);
  }
  #pragma unroll
  for (int mf=0;mf<2;++mf)
    #pragma unroll
    for (int nf=0;nf<4;++nf)
      #pragma unroll
      for (int r=0;r<4;++r){
        int rowc = m0 + w*32 + mf*16 + (l>>4)*4 + r;
        int col = g*64 + nf*16 + (l&15);
        U[(size_t)b*1048576 + (size_t)rowc*1024 + col] = (bf16)acc[mf][nf][r];
      }
}

// ---------- LayerNorm: wave per row of 1024 ----------
__global__ __launch_bounds__(256) void k_ln(const bf16* __restrict__ h, const float* __restrict__ gamma,
                                            const float* __restrict__ beta, float* __restrict__ y){
  const int w = threadIdx.x>>6, l = threadIdx.x&63;
  const size_t row = (size_t)blockIdx.x*4 + w;
  const bf16* hr = h + row*1024 + l*16;
  uint4 p0 = *(const uint4*)hr;
  uint4 p1 = *(const uint4*)(hr+8);
  float v[16];
  const uint32_t* pw = (const uint32_t*)&p0;
  #pragma unroll
  for (int i=0;i<4;++i){ v[2*i] = bits2f(pw[i]<<16); v[2*i+1] = bits2f(pw[i]&0xffff0000u); }
  const uint32_t* pw1 = (const uint32_t*)&p1;
  #pragma unroll
  for (int i=0;i<4;++i){ v[8+2*i] = bits2f(pw1[i]<<16); v[8+2*i+1] = bits2f(pw1[i]&0xffff0000u); }
  float s=0.f, s2=0.f;
  #pragma unroll
  for (int i=0;i<16;++i){ s+=v[i]; s2+=v[i]*v[i]; }
  #pragma unroll
  for (int off=1; off<64; off<<=1){ s += __shfl_xor(s,off); s2 += __shfl_xor(s2,off); }
  float mu = s*(1.0f/1024.0f);
  float var = s2*(1.0f/1024.0f) - mu*mu;
  float rinv = rsqrtf(var + 1e-5f);
  const float* gp = gamma + l*16; const float* bp = beta + l*16;
  float o[16];
  #pragma unroll
  for (int i=0;i<16;++i) o[i] = gp[i]*(v[i]-mu)*rinv + bp[i];
  float* yr = y + row*1024 + l*16;
  #pragma unroll
  for (int i=0;i<4;++i) ((float4*)yr)[i] = *(float4*)&o[4*i];
}

extern "C" void kernel_launch(void* const* d_in, const int* in_sizes, int n_in,
                              void* d_out, int out_size, void* d_ws, size_t ws_size,
                              hipStream_t stream){
  const float* x     = (const float*)d_in[0];
  const float* Wqkv  = (const float*)d_in[1];
  const float* Wproj = (const float*)d_in[2];
  const float* bproj = (const float*)d_in[3];
  const float* gamma = (const float*)d_in[4];
  const float* beta  = (const float*)d_in[5];
  float* y = (float*)d_out;

  char* ws = (char*)d_ws;
  size_t off = 0;
  auto alloc = [&](size_t bytes)->void*{ void* p = ws + off; off += (bytes + 255) & ~(size_t)255; return p; };
  bf16* xb     = (bf16*)alloc((size_t)32768*1024*2);   // 67.1 MB
  bf16* xT     = (bf16*)alloc((size_t)8*1024*4096*2);  // 67.1 MB (reused as h)
  bf16* Wqkvb  = (bf16*)alloc((size_t)1024*3072*2);
  bf16* WqkvT  = (bf16*)alloc((size_t)3072*1024*2);
  bf16* WprojT = (bf16*)alloc((size_t)1024*1024*2);
  bf16* Gram   = (bf16*)alloc((size_t)8*1024*1024*2);  // 16.8 MB
  bf16* T2     = (bf16*)alloc((size_t)8*1024*1024*2);
  bf16* Aatt   = (bf16*)alloc((size_t)128*64*64*2);
  bf16* U      = (bf16*)alloc((size_t)8*1024*1024*2);
  bf16* WeffT  = (bf16*)alloc((size_t)8*1024*1024*2);
  bf16* h      = xT;   // xT dead after Gram

  const size_t MB1 = 1048576;

  k_cast<<<16384,256,0,stream>>>(x, xb, 33554432);
  k_cast<<<1536,256,0,stream>>>(Wqkv, Wqkvb, 3145728);
  k_transpose<<<dim3(96,32,1),256,0,stream>>>(Wqkv, WqkvT, 1024, 3072, 0, 0);
  k_transpose<<<dim3(32,32,1),256,0,stream>>>(Wproj, WprojT, 1024, 1024, 0, 0);
  // xT_b[c][n] = x_b[n][c]
  k_transpose<<<dim3(32,128,8),256,0,stream>>>(x, xT, 4096, 1024, (size_t)4096*1024, (size_t)1024*4096);
  // Gram_b = xT_b @ xT_b^T  [1024x1024], K=4096
  k_gemm128<<<dim3(8,8,8),256,0,stream>>>(xT, xT, Gram, 1024, 4096, 4096, 4096,
                                          (size_t)1024*4096, (size_t)1024*4096, MB1);
  // T2_b = Wk^T @ Gram_b  [1024x1024], K=1024  (Wk^T = WqkvT rows 1024..2047; Gram symmetric)
  k_gemm128<<<dim3(8,8,8),256,0,stream>>>(WqkvT + (size_t)1024*1024, Gram, T2, 1024, 1024, 1024, 1024,
                                          0, MB1, MB1);
  // S + softmax -> Aatt
  k_sgemm64<<<128,256,0,stream>>>(T2, WqkvT, Aatt);
  // U_b[:, g-block] = Wq_g @ Aatt_bg^T
  k_applyW<<<dim3(8,128),256,0,stream>>>(Wqkvb, Aatt, U);
  // WeffT_b = WprojT @ U_b^T  [1024x1024], K=1024
  k_gemm128<<<dim3(8,8,8),256,0,stream>>>(WprojT, U, WeffT, 1024, 1024, 1024, 1024,
                                          0, MB1, MB1);
  // h_b = xb_b @ WeffT_b^T + bproj + x_b   [4096x1024] per batch
  k_gemm256<<<dim3(4,16,8),512,0,stream>>>(xb, WeffT, h, 1024, 1024, bproj, x,
                                           (size_t)4096*1024, MB1, (size_t)4096*1024, (size_t)4096*1024);
  k_ln<<<8192,256,0,stream>>>(h, gamma, beta, y);
}

// Round 7
// 350.465 us; speedup vs baseline: 2.9158x; 1.1490x over previous
//
#include <hip/hip_runtime.h>
#include <cstdint>

typedef __bf16 bf16;
typedef __bf16 bf16x8 __attribute__((ext_vector_type(8)));
typedef float f32x4 __attribute__((ext_vector_type(4)));

#define DEVI __device__ __forceinline__

DEVI float bits2f(uint32_t u){ union{uint32_t u;float f;}x; x.u=u; return x.f; }

DEVI void gload_lds16(const void* g, void* l){
  __builtin_amdgcn_global_load_lds(
    (const __attribute__((address_space(1))) uint32_t*)g,
    (__attribute__((address_space(3))) uint32_t*)l, 16, 0, 0);
}

// ---------- cast fp32 -> bf16, 8 elems/thread ----------
__global__ __launch_bounds__(256) void k_cast(const float* __restrict__ x, bf16* __restrict__ o, int n){
  int i = (blockIdx.x*256 + threadIdx.x)*8;
  if (i >= n) return;
  float4 a = *(const float4*)(x+i);
  float4 b = *(const float4*)(x+i+4);
  union { bf16 h[8]; uint4 u; } r;
  r.h[0]=(bf16)a.x; r.h[1]=(bf16)a.y; r.h[2]=(bf16)a.z; r.h[3]=(bf16)a.w;
  r.h[4]=(bf16)b.x; r.h[5]=(bf16)b.y; r.h[6]=(bf16)b.z; r.h[7]=(bf16)b.w;
  *(uint4*)(o+i) = r.u;
}

// ---------- fused: read x fp32 once -> xb (bf16, same layout) + xT (bf16, transposed) ----------
// 64x64 tile; LDS [64][65] fp32 (pad 65 => all LDS access <=2-way conflict, free).
__global__ __launch_bounds__(256) void k_castT(const float* __restrict__ x, bf16* __restrict__ xb,
                                               bf16* __restrict__ xT){
  const int b = blockIdx.z;
  x  += (size_t)b*4194304; xb += (size_t)b*4194304; xT += (size_t)b*4194304;
  const int n0 = blockIdx.y*64, c0 = blockIdx.x*64;
  __shared__ float sF[64][65];
  const int t = threadIdx.x;
  const int lr = t>>4, lc4 = (t&15)*4;
  #pragma unroll
  for (int i=0;i<4;++i){
    int r = lr + i*16;
    float4 v = *(const float4*)(x + (size_t)(n0+r)*1024 + c0 + lc4);
    sF[r][lc4+0]=v.x; sF[r][lc4+1]=v.y; sF[r][lc4+2]=v.z; sF[r][lc4+3]=v.w;
  }
  __syncthreads();
  const int wr = t>>3, wc8 = (t&7)*8;
  #pragma unroll
  for (int i=0;i<2;++i){
    int r = wr + i*32;
    union{ bf16 h[8]; uint4 u; } p;
    #pragma unroll
    for (int j=0;j<8;++j) p.h[j] = (bf16)sF[r][wc8+j];
    *(uint4*)(xb + (size_t)(n0+r)*1024 + c0 + wc8) = p.u;
  }
  #pragma unroll
  for (int i=0;i<2;++i){
    int c = wr + i*32;
    union{ bf16 h[8]; uint4 u; } p;
    #pragma unroll
    for (int j=0;j<8;++j) p.h[j] = (bf16)sF[wc8+j][c];
    *(uint4*)(xT + (size_t)(c0+c)*4096 + n0 + wc8) = p.u;
  }
}

// ---------- transpose + cast: WT[c][r] = W[r][c] ----------
__global__ __launch_bounds__(256) void k_transpose(const float* __restrict__ W, bf16* __restrict__ WT,
                                                   int R, int Ccols){
  __shared__ float tile[32][33];
  int bc = blockIdx.x*32, br = blockIdx.y*32;
  int lc = threadIdx.x & 31, lr = threadIdx.x >> 5; // lr 0..7
  #pragma unroll
  for (int i=0;i<4;i++){
    int r = lr + i*8;
    tile[r][lc] = W[(size_t)(br+r)*Ccols + bc + lc];
  }
  __syncthreads();
  #pragma unroll
  for (int i=0;i<4;i++){
    int r = lr + i*8;
    WT[(size_t)(bc+r)*R + br + lc] = (bf16)tile[lc][r];
  }
}

// =====================================================================
// 128x128-tile bf16 GEMM (r1 structure, verified 841 TF), batched via z.
// C[m][n] = sum_k A[m][k] * BT[n][k].  lda/ldb decoupled from K.
// =====================================================================
__global__ __launch_bounds__(256) void k_gemm128(
    const bf16* __restrict__ A, const bf16* __restrict__ BT, bf16* __restrict__ C,
    int N, int K, int lda, int ldb,
    size_t As, size_t Bs, size_t Cs)
{
  A += blockIdx.z*As; BT += blockIdx.z*Bs; C += blockIdx.z*Cs;
  __shared__ __align__(16) bf16 sA[128*64];
  __shared__ __align__(16) bf16 sB[128*64];
  const int t = threadIdx.x, w = t>>6, l = t&63;
  const int bm = blockIdx.y*128, bn = blockIdx.x*128;
  const int wr = (w>>1)*64, wc = (w&1)*64;
  f32x4 acc[4][4] = {};
  const int srow = l>>3;                      // row within chunk (0..7) == row&7
  const int scol = ((l&7) ^ (l>>3))*8;        // swizzled source col (elements)
  const int nk = K>>6;
  for (int kt=0; kt<nk; ++kt) {
    const int k0 = kt*64;
    #pragma unroll
    for (int i=0;i<4;++i){
      int c = w*4+i;
      int row = c*8 + srow;
      gload_lds16(A  + (size_t)(bm+row)*lda + k0 + scol, (char*)sA + c*1024);
      gload_lds16(BT + (size_t)(bn+row)*ldb + k0 + scol, (char*)sB + c*1024);
    }
    __syncthreads();
    #pragma unroll
    for (int kk=0; kk<64; kk+=32) {
      bf16x8 af[4], bfr[4];
      const int xr = ((kk + 8*(l>>4))*2) ^ ((l&7)<<4);
      #pragma unroll
      for (int mf=0;mf<4;++mf){
        int row = wr + mf*16 + (l&15);
        af[mf] = *(const bf16x8*)((const char*)sA + row*128 + xr);
      }
      #pragma unroll
      for (int nf=0;nf<4;++nf){
        int row = wc + nf*16 + (l&15);
        bfr[nf] = *(const bf16x8*)((const char*)sB + row*128 + xr);
      }
      #pragma unroll
      for (int mf=0;mf<4;++mf)
        #pragma unroll
        for (int nf=0;nf<4;++nf)
          acc[mf][nf] = __builtin_amdgcn_mfma_f32_16x16x32_bf16(af[mf], bfr[nf], acc[mf][nf], 0,0,0);
    }
    __syncthreads();
  }
  #pragma unroll
  for (int mf=0;mf<4;++mf)
    #pragma unroll
    for (int nf=0;nf<4;++nf)
      #pragma unroll
      for (int r=0;r<4;++r){
        int row = bm + wr + mf*16 + (l>>4)*4 + r;
        int col = bn + wc + nf*16 + (l&15);
        C[(size_t)row*N + col] = (bf16)acc[mf][nf][r];
      }
}

// =====================================================================
// 256x256-tile pipelined GEMM (r3 structure) with fused epilogue:
// C = bf16(A*BT^T + bias + resid), resid bf16, batched via z.
// =====================================================================
__global__ __launch_bounds__(512, 2) void k_gemm256(
    const bf16* __restrict__ A, const bf16* __restrict__ BT, bf16* __restrict__ C,
    int N, int K,
    const float* __restrict__ bias, const bf16* __restrict__ resid,
    size_t As, size_t Bs, size_t Cs, size_t Rs)
{
  A += blockIdx.z*As; BT += blockIdx.z*Bs; C += blockIdx.z*Cs; resid += blockIdx.z*Rs;
  __shared__ __align__(16) bf16 lds[2][2][256*64];   // 128 KiB
  bf16* bA0 = &lds[0][0][0]; bf16* bB0 = &lds[0][1][0];
  bf16* bA1 = &lds[1][0][0]; bf16* bB1 = &lds[1][1][0];

  const int t = threadIdx.x, w = t>>6, l = t&63;
  const int wm = w>>2, wn = w&3;

  const int nwg = gridDim.x * gridDim.y;
  const int orig = blockIdx.y * gridDim.x + blockIdx.x;
  const int q = nwg >> 3, r = nwg & 7;
  const int xcd = orig & 7, loc = orig >> 3;
  const int swz = (xcd < r ? xcd*(q+1) : r*(q+1) + (xcd-r)*q) + loc;
  const int bx = swz % gridDim.x, by = swz / gridDim.x;
  const int bm = by*256, bn = bx*256;

  const int co0 = (16*(l>>4)) ^ ((l&7)<<4);
  const int co1 = (64 + 16*(l>>4)) ^ ((l&7)<<4);

  auto stageA = [&](const bf16* G, bf16* Ldst, int j, int k0){
    int row = wm*128 + wn*32 + j*8 + (l>>3);
    int col = 8*((l&7) ^ (l>>3));
    gload_lds16(G + (size_t)(bm + row)*K + k0 + col,
                Ldst + (wm*128 + wn*32 + j*8)*64);
  };
  auto stageB = [&](const bf16* G, bf16* Ldst, int j, int k0){
    int row = j*64 + w*8 + (l>>3);
    int col = 8*((l&7) ^ (l>>3));
    gload_lds16(G + (size_t)(bn + row)*K + k0 + col,
                Ldst + (j*64 + w*8)*64);
  };

#define RD_AA(dst, qd, base) {                                                  \
    const int r0 = wm*128 + (qd)*32 + (l&15);                                   \
    dst[0][0] = *(const bf16x8*)((const char*)(base) + (r0   )*128 + co0);      \
    dst[0][1] = *(const bf16x8*)((const char*)(base) + (r0   )*128 + co1);      \
    dst[1][0] = *(const bf16x8*)((const char*)(base) + (r0+16)*128 + co0);      \
    dst[1][1] = *(const bf16x8*)((const char*)(base) + (r0+16)*128 + co1);      \
  }

#define MFMA_Q(P, AA) {                                                         \
    __builtin_amdgcn_s_setprio(1);                                              \
    _Pragma("unroll")                                                           \
    for (int kk=0;kk<2;++kk)                                                    \
      _Pragma("unroll")                                                         \
      for (int i=0;i<2;++i)                                                     \
        _Pragma("unroll")                                                       \
        for (int nf=0;nf<4;++nf)                                                \
          acc[2*(P)+i][nf] = __builtin_amdgcn_mfma_f32_16x16x32_bf16(           \
              AA[i][kk], bfr[nf][kk], acc[2*(P)+i][nf], 0,0,0);                 \
    __builtin_amdgcn_s_setprio(0);                                              \
  }

#define BAR asm volatile("s_barrier" ::: "memory")

  f32x4 acc[8][4] = {};
  const int NT = K >> 6;

  #pragma unroll
  for (int j=0;j<4;++j) stageA(A, bA0, j, 0);
  #pragma unroll
  for (int j=0;j<4;++j) stageB(BT, bB0, j, 0);
  __builtin_amdgcn_sched_barrier(0);
  if (NT > 1){
    #pragma unroll
    for (int j=0;j<4;++j) stageB(BT, bB1, j, 64);
    asm volatile("s_waitcnt vmcnt(4)" ::: "memory");
  } else {
    asm volatile("s_waitcnt vmcnt(0)" ::: "memory");
  }
  BAR;

  bf16x8 aaA[2][2], aaB[2][2];
  RD_AA(aaA, wn, bA0);

  for (int T = 0; T < NT; ++T){
    bf16* sA  = (T&1) ? bA1 : bA0;
    bf16* sB  = (T&1) ? bB1 : bB0;
    bf16* sAn = (T&1) ? bA0 : bA1;
    const int kA = (T+1)<<6, kB = (T+2)<<6;
    const bool stA = (T+1) < NT, stB = (T+2) < NT;

    bf16x8 bfr[4][2];
    const int rb = wn*64 + (l&15);
    #pragma unroll
    for (int nf=0;nf<4;++nf){
      bfr[nf][0] = *(const bf16x8*)((const char*)sB + (rb+nf*16)*128 + co0);
      bfr[nf][1] = *(const bf16x8*)((const char*)sB + (rb+nf*16)*128 + co1);
    }

    RD_AA(aaB, (wn+1)&3, sA);
    if (stA){ stageA(A, sAn, 0, kA); stageA(A, sAn, 1, kA); }
    BAR; MFMA_Q(0, aaA); BAR;

    RD_AA(aaA, (wn+2)&3, sA);
    if (stA){ stageA(A, sAn, 2, kA); stageA(A, sAn, 3, kA); }
    BAR; MFMA_Q(1, aaB); BAR;

    RD_AA(aaB, (wn+3)&3, sA);
    if (stB){ stageB(BT, sB, 0, kB); stageB(BT, sB, 1, kB); }
    BAR; MFMA_Q(2, aaA); BAR;

    if (stB){
      stageB(BT, sB, 2, kB); stageB(BT, sB, 3, kB);
      asm volatile("s_waitcnt vmcnt(4)" ::: "memory");
    } else {
      asm volatile("s_waitcnt vmcnt(0)" ::: "memory");
    }
    if (stA) RD_AA(aaA, wn, sAn);
    BAR; MFMA_Q(3, aaB); BAR;
  }
#undef RD_AA
#undef MFMA_Q
#undef BAR

  #pragma unroll
  for (int P=0; P<4; ++P){
    const int qd = (P+wn)&3;
    #pragma unroll
    for (int i=0;i<2;++i){
      #pragma unroll
      for (int nf=0; nf<4; ++nf){
        #pragma unroll
        for (int r2=0; r2<4; ++r2){
          int row = bm + wm*128 + qd*32 + i*16 + (l>>4)*4 + r2;
          int col = bn + wn*64 + nf*16 + (l&15);
          float v = acc[2*P+i][nf][r2] + bias[col] + (float)resid[(size_t)row*N + col];
          C[(size_t)row*N + col] = (bf16)v;
        }
      }
    }
  }
}

// ---------- fused S = scale * T2_g @ Wv_g^T + row softmax -> Aatt[bg][64][64] ----------
__global__ __launch_bounds__(256) void k_sgemm64(const bf16* __restrict__ T2, const bf16* __restrict__ WqkvT,
                                                 bf16* __restrict__ Aatt){
  const int bg = blockIdx.x, b = bg>>4, g = bg&15;
  const bf16* Arows = T2 + (size_t)b*1048576 + (size_t)(g*64)*1024;   // [64][1024] rows d
  const bf16* Brows = WqkvT + (size_t)(2048 + g*64)*1024;             // [64][1024] rows e (Wv cols)
  __shared__ __align__(16) bf16 sA[64*64];
  __shared__ __align__(16) bf16 sB[64*64];
  const int t = threadIdx.x, w = t>>6, l = t&63;
  const int srow = l>>3, scol = ((l&7)^(l>>3))*8;
  f32x4 acc[4] = {};
  for (int kt=0; kt<16; ++kt){
    const int k0 = kt*64;
    gload_lds16(Arows + (size_t)(w*8+srow)*1024 + k0 + scol,      sA + (w*8)*64);
    gload_lds16(Arows + (size_t)(32+w*8+srow)*1024 + k0 + scol,   sA + (32+w*8)*64);
    gload_lds16(Brows + (size_t)(w*8+srow)*1024 + k0 + scol,      sB + (w*8)*64);
    gload_lds16(Brows + (size_t)(32+w*8+srow)*1024 + k0 + scol,   sB + (32+w*8)*64);
    __syncthreads();
    #pragma unroll
    for (int kk=0; kk<64; kk+=32){
      const int xr = ((kk + 8*(l>>4))*2) ^ ((l&7)<<4);
      bf16x8 af = *(const bf16x8*)((const char*)sA + (w*16+(l&15))*128 + xr);
      #pragma unroll
      for (int nf=0; nf<4; ++nf){
        bf16x8 bfv = *(const bf16x8*)((const char*)sB + (nf*16+(l&15))*128 + xr);
        acc[nf] = __builtin_amdgcn_mfma_f32_16x16x32_bf16(af, bfv, acc[nf], 0,0,0);
      }
    }
    __syncthreads();
  }
  #pragma unroll
  for (int reg=0; reg<4; ++reg){
    float m = -3.4e38f;
    #pragma unroll
    for (int nf=0; nf<4; ++nf) m = fmaxf(m, acc[nf][reg]);
    m = fmaxf(m, __shfl_xor(m,1)); m = fmaxf(m, __shfl_xor(m,2));
    m = fmaxf(m, __shfl_xor(m,4)); m = fmaxf(m, __shfl_xor(m,8));
    float e[4]; float s = 0.f;
    #pragma unroll
    for (int nf=0; nf<4; ++nf){ e[nf] = __expf((acc[nf][reg]-m)*0.125f); s += e[nf]; }
    s += __shfl_xor(s,1); s += __shfl_xor(s,2); s += __shfl_xor(s,4); s += __shfl_xor(s,8);
    const float inv = 1.0f/s;
    const int row = w*16 + (l>>4)*4 + reg;
    #pragma unroll
    for (int nf=0; nf<4; ++nf)
      Aatt[(size_t)bg*4096 + row*64 + nf*16 + (l&15)] = (bf16)(e[nf]*inv);
  }
}

// ---------- U[c][g*64+d] = sum_e Wq[c][g*64+e] * Aatt_bg[d][e] ----------
__global__ __launch_bounds__(256) void k_applyW(const bf16* __restrict__ Wqkvb, const bf16* __restrict__ Aatt,
                                                bf16* __restrict__ U){
  const int bg = blockIdx.y, b = bg>>4, g = bg&15;
  const int m0 = blockIdx.x*128;
  __shared__ __align__(16) bf16 Pl[64][72];
  const int t = threadIdx.x, w = t>>6, l = t&63;
  for (int idx=t; idx<1024; idx+=256){
    int r2 = idx>>4, c4 = (idx&15)*4;
    *(uint2*)&Pl[r2][c4] = *(const uint2*)&Aatt[(size_t)bg*4096 + r2*64 + c4];
  }
  __syncthreads();
  f32x4 acc[2][4] = {};
  const bf16* Ab = Wqkvb + (size_t)(m0 + w*32)*3072 + g*64;
  #pragma unroll
  for (int kk=0; kk<64; kk+=32){
    bf16x8 af[2], pf[4];
    #pragma unroll
    for (int mf=0;mf<2;++mf)
      af[mf] = *(const bf16x8*)(Ab + (size_t)(mf*16 + (l&15))*3072 + kk + 8*(l>>4));
    #pragma unroll
    for (int nf=0;nf<4;++nf)
      pf[nf] = *(const bf16x8*)&Pl[nf*16 + (l&15)][kk + 8*(l>>4)];
    #pragma unroll
    for (int mf=0;mf<2;++mf)
      #pragma unroll
      for (int nf=0;nf<4;++nf)
        acc[mf][nf] = __builtin_amdgcn_mfma_f32_16x16x32_bf16(af[mf], pf[nf], acc[mf][nf], 0,0,0);
  }
  #pragma unroll
  for (int mf=0;mf<2;++mf)
    #pragma unroll
    for (int nf=0;nf<4;++nf)
      #pragma unroll
      for (int r=0;r<4;++r){
        int rowc = m0 + w*32 + mf*16 + (l>>4)*4 + r;
        int col = g*64 + nf*16 + (l&15);
        U[(size_t)b*1048576 + (size_t)rowc*1024 + col] = (bf16)acc[mf][nf][r];
      }
}

// ---------- LayerNorm: wave per row of 1024 ----------
__global__ __launch_bounds__(256) void k_ln(const bf16* __restrict__ h, const float* __restrict__ gamma,
                                            const float* __restrict__ beta, float* __restrict__ y){
  const int w = threadIdx.x>>6, l = threadIdx.x&63;
  const size_t row = (size_t)blockIdx.x*4 + w;
  const bf16* hr = h + row*1024 + l*16;
  uint4 p0 = *(const uint4*)hr;
  uint4 p1 = *(const uint4*)(hr+8);
  float v[16];
  const uint32_t* pw = (const uint32_t*)&p0;
  #pragma unroll
  for (int i=0;i<4;++i){ v[2*i] = bits2f(pw[i]<<16); v[2*i+1] = bits2f(pw[i]&0xffff0000u); }
  const uint32_t* pw1 = (const uint32_t*)&p1;
  #pragma unroll
  for (int i=0;i<4;++i){ v[8+2*i] = bits2f(pw1[i]<<16); v[8+2*i+1] = bits2f(pw1[i]&0xffff0000u); }
  float s=0.f, s2=0.f;
  #pragma unroll
  for (int i=0;i<16;++i){ s+=v[i]; s2+=v[i]*v[i]; }
  #pragma unroll
  for (int off=1; off<64; off<<=1){ s += __shfl_xor(s,off); s2 += __shfl_xor(s2,off); }
  float mu = s*(1.0f/1024.0f);
  float var = s2*(1.0f/1024.0f) - mu*mu;
  float rinv = rsqrtf(var + 1e-5f);
  const float* gp = gamma + l*16; const float* bp = beta + l*16;
  float o[16];
  #pragma unroll
  for (int i=0;i<16;++i) o[i] = gp[i]*(v[i]-mu)*rinv + bp[i];
  float* yr = y + row*1024 + l*16;
  #pragma unroll
  for (int i=0;i<4;++i) ((float4*)yr)[i] = *(float4*)&o[4*i];
}

extern "C" void kernel_launch(void* const* d_in, const int* in_sizes, int n_in,
                              void* d_out, int out_size, void* d_ws, size_t ws_size,
                              hipStream_t stream){
  const float* x     = (const float*)d_in[0];
  const float* Wqkv  = (const float*)d_in[1];
  const float* Wproj = (const float*)d_in[2];
  const float* bproj = (const float*)d_in[3];
  const float* gamma = (const float*)d_in[4];
  const float* beta  = (const float*)d_in[5];
  float* y = (float*)d_out;

  char* ws = (char*)d_ws;
  size_t off = 0;
  auto alloc = [&](size_t bytes)->void*{ void* p = ws + off; off += (bytes + 255) & ~(size_t)255; return p; };
  bf16* xb     = (bf16*)alloc((size_t)32768*1024*2);   // 67.1 MB
  bf16* xT     = (bf16*)alloc((size_t)8*1024*4096*2);  // 67.1 MB (reused as h)
  bf16* Wqkvb  = (bf16*)alloc((size_t)1024*3072*2);
  bf16* WqkvT  = (bf16*)alloc((size_t)3072*1024*2);
  bf16* WprojT = (bf16*)alloc((size_t)1024*1024*2);
  bf16* Gram   = (bf16*)alloc((size_t)8*1024*1024*2);  // 16.8 MB
  bf16* T2     = (bf16*)alloc((size_t)8*1024*1024*2);
  bf16* Aatt   = (bf16*)alloc((size_t)128*64*64*2);
  bf16* U      = (bf16*)alloc((size_t)8*1024*1024*2);
  bf16* WeffT  = (bf16*)alloc((size_t)8*1024*1024*2);
  bf16* h      = xT;   // xT dead after Gram

  const size_t MB1 = 1048576;

  // x -> xb + xT in one pass (reads x once)
  k_castT<<<dim3(16,64,8),256,0,stream>>>(x, xb, xT);
  k_cast<<<1536,256,0,stream>>>(Wqkv, Wqkvb, 3145728);
  k_transpose<<<dim3(96,32),256,0,stream>>>(Wqkv, WqkvT, 1024, 3072);
  k_transpose<<<dim3(32,32),256,0,stream>>>(Wproj, WprojT, 1024, 1024);
  // Gram_b = xT_b @ xT_b^T  [1024x1024], K=4096
  k_gemm128<<<dim3(8,8,8),256,0,stream>>>(xT, xT, Gram, 1024, 4096, 4096, 4096,
                                          (size_t)1024*4096, (size_t)1024*4096, MB1);
  // T2_b = Wk^T @ Gram_b  [1024x1024], K=1024  (Gram symmetric)
  k_gemm128<<<dim3(8,8,8),256,0,stream>>>(WqkvT + (size_t)1024*1024, Gram, T2, 1024, 1024, 1024, 1024,
                                          0, MB1, MB1);
  // S + softmax -> Aatt
  k_sgemm64<<<128,256,0,stream>>>(T2, WqkvT, Aatt);
  // U_b[:, g-block] = Wq_g @ Aatt_bg^T
  k_applyW<<<dim3(8,128),256,0,stream>>>(Wqkvb, Aatt, U);
  // WeffT_b = WprojT @ U_b^T  [1024x1024], K=1024
  k_gemm128<<<dim3(8,8,8),256,0,stream>>>(WprojT, U, WeffT, 1024, 1024, 1024, 1024,
                                          0, MB1, MB1);
  // h_b = xb_b @ WeffT_b^T + bproj + xb_b   [4096x1024] per batch (resid bf16)
  k_gemm256<<<dim3(4,16,8),512,0,stream>>>(xb, WeffT, h, 1024, 1024, bproj, xb,
                                           (size_t)4096*1024, MB1, (size_t)4096*1024, (size_t)4096*1024);
  k_ln<<<8192,256,0,stream>>>(h, gamma, beta, y);
}

// Round 8
// 333.407 us; speedup vs baseline: 3.0649x; 1.0512x over previous
//
#include <hip/hip_runtime.h>
#include <cstdint>

typedef __bf16 bf16;
typedef __bf16 bf16x8 __attribute__((ext_vector_type(8)));
typedef float f32x4 __attribute__((ext_vector_type(4)));

#define DEVI __device__ __forceinline__

DEVI float bits2f(uint32_t u){ union{uint32_t u;float f;}x; x.u=u; return x.f; }
DEVI uint32_t packbf2(float a, float b){
  union{ bf16 h[2]; uint32_t u; } p; p.h[0]=(bf16)a; p.h[1]=(bf16)b; return p.u;
}

DEVI void gload_lds16(const void* g, void* l){
  __builtin_amdgcn_global_load_lds(
    (const __attribute__((address_space(1))) uint32_t*)g,
    (__attribute__((address_space(3))) uint32_t*)l, 16, 0, 0);
}

// ---------- cast fp32 -> bf16, 8 elems/thread ----------
__global__ __launch_bounds__(256) void k_cast(const float* __restrict__ x, bf16* __restrict__ o, int n){
  int i = (blockIdx.x*256 + threadIdx.x)*8;
  if (i >= n) return;
  float4 a = *(const float4*)(x+i);
  float4 b = *(const float4*)(x+i+4);
  union { bf16 h[8]; uint4 u; } r;
  r.h[0]=(bf16)a.x; r.h[1]=(bf16)a.y; r.h[2]=(bf16)a.z; r.h[3]=(bf16)a.w;
  r.h[4]=(bf16)b.x; r.h[5]=(bf16)b.y; r.h[6]=(bf16)b.z; r.h[7]=(bf16)b.w;
  *(uint4*)(o+i) = r.u;
}

// ---------- fused: read x fp32 once -> xb (bf16) + xT (bf16 transposed) ----------
__global__ __launch_bounds__(256) void k_castT(const float* __restrict__ x, bf16* __restrict__ xb,
                                               bf16* __restrict__ xT){
  const int b = blockIdx.z;
  x  += (size_t)b*4194304; xb += (size_t)b*4194304; xT += (size_t)b*4194304;
  const int n0 = blockIdx.y*64, c0 = blockIdx.x*64;
  __shared__ float sF[64][65];
  const int t = threadIdx.x;
  const int lr = t>>4, lc4 = (t&15)*4;
  #pragma unroll
  for (int i=0;i<4;++i){
    int r = lr + i*16;
    float4 v = *(const float4*)(x + (size_t)(n0+r)*1024 + c0 + lc4);
    sF[r][lc4+0]=v.x; sF[r][lc4+1]=v.y; sF[r][lc4+2]=v.z; sF[r][lc4+3]=v.w;
  }
  __syncthreads();
  const int wr = t>>3, wc8 = (t&7)*8;
  #pragma unroll
  for (int i=0;i<2;++i){
    int r = wr + i*32;
    union{ bf16 h[8]; uint4 u; } p;
    #pragma unroll
    for (int j=0;j<8;++j) p.h[j] = (bf16)sF[r][wc8+j];
    *(uint4*)(xb + (size_t)(n0+r)*1024 + c0 + wc8) = p.u;
  }
  #pragma unroll
  for (int i=0;i<2;++i){
    int c = wr + i*32;
    union{ bf16 h[8]; uint4 u; } p;
    #pragma unroll
    for (int j=0;j<8;++j) p.h[j] = (bf16)sF[wc8+j][c];
    *(uint4*)(xT + (size_t)(c0+c)*4096 + n0 + wc8) = p.u;
  }
}

// ---------- transpose + cast: WT[c][r] = W[r][c] ----------
__global__ __launch_bounds__(256) void k_transpose(const float* __restrict__ W, bf16* __restrict__ WT,
                                                   int R, int Ccols){
  __shared__ float tile[32][33];
  int bc = blockIdx.x*32, br = blockIdx.y*32;
  int lc = threadIdx.x & 31, lr = threadIdx.x >> 5;
  #pragma unroll
  for (int i=0;i<4;i++){
    int r = lr + i*8;
    tile[r][lc] = W[(size_t)(br+r)*Ccols + bc + lc];
  }
  __syncthreads();
  #pragma unroll
  for (int i=0;i<4;i++){
    int r = lr + i*8;
    WT[(size_t)(bc+r)*R + br + lc] = (bf16)tile[lc][r];
  }
}

// =====================================================================
// 128x128-tile bf16 GEMM (r1 structure), batched via z.
// =====================================================================
__global__ __launch_bounds__(256) void k_gemm128(
    const bf16* __restrict__ A, const bf16* __restrict__ BT, bf16* __restrict__ C,
    int N, int K, int lda, int ldb,
    size_t As, size_t Bs, size_t Cs)
{
  A += blockIdx.z*As; BT += blockIdx.z*Bs; C += blockIdx.z*Cs;
  __shared__ __align__(16) bf16 sA[128*64];
  __shared__ __align__(16) bf16 sB[128*64];
  const int t = threadIdx.x, w = t>>6, l = t&63;
  const int bm = blockIdx.y*128, bn = blockIdx.x*128;
  const int wr = (w>>1)*64, wc = (w&1)*64;
  f32x4 acc[4][4] = {};
  const int srow = l>>3;
  const int scol = ((l&7) ^ (l>>3))*8;
  const int nk = K>>6;
  for (int kt=0; kt<nk; ++kt) {
    const int k0 = kt*64;
    #pragma unroll
    for (int i=0;i<4;++i){
      int c = w*4+i;
      int row = c*8 + srow;
      gload_lds16(A  + (size_t)(bm+row)*lda + k0 + scol, (char*)sA + c*1024);
      gload_lds16(BT + (size_t)(bn+row)*ldb + k0 + scol, (char*)sB + c*1024);
    }
    __syncthreads();
    #pragma unroll
    for (int kk=0; kk<64; kk+=32) {
      bf16x8 af[4], bfr[4];
      const int xr = ((kk + 8*(l>>4))*2) ^ ((l&7)<<4);
      #pragma unroll
      for (int mf=0;mf<4;++mf){
        int row = wr + mf*16 + (l&15);
        af[mf] = *(const bf16x8*)((const char*)sA + row*128 + xr);
      }
      #pragma unroll
      for (int nf=0;nf<4;++nf){
        int row = wc + nf*16 + (l&15);
        bfr[nf] = *(const bf16x8*)((const char*)sB + row*128 + xr);
      }
      #pragma unroll
      for (int mf=0;mf<4;++mf)
        #pragma unroll
        for (int nf=0;nf<4;++nf)
          acc[mf][nf] = __builtin_amdgcn_mfma_f32_16x16x32_bf16(af[mf], bfr[nf], acc[mf][nf], 0,0,0);
    }
    __syncthreads();
  }
  #pragma unroll
  for (int mf=0;mf<4;++mf)
    #pragma unroll
    for (int nf=0;nf<4;++nf)
      #pragma unroll
      for (int r=0;r<4;++r){
        int row = bm + wr + mf*16 + (l>>4)*4 + r;
        int col = bn + wc + nf*16 + (l&15);
        C[(size_t)row*N + col] = (bf16)acc[mf][nf][r];
      }
}

// =====================================================================
// Gram = xT_b @ xT_b^T (symmetric): upper-triangle tiles only (36/batch),
// mirror off-diag tiles via LDS transpose. XCD-chunked remap: each XCD
// owns one batch (d%8 = XCD under round-robin dispatch).
// Grid: dim3(36,8), 256 threads.
// =====================================================================
__global__ __launch_bounds__(256) void k_gramsym(const bf16* __restrict__ xT, bf16* __restrict__ Gram){
  const int d = blockIdx.y*36 + blockIdx.x;
  const int vt = (d & 7)*36 + (d >> 3);     // chunk remap: XCD = d%8 -> batch
  const int b = vt/36;
  int t36 = vt - b*36;
  int i = 0;
  while (t36 >= 8 - i){ t36 -= 8 - i; ++i; }
  const int j = i + t36;                     // i <= j
  const bf16* A = xT + (size_t)b*4194304;
  bf16* C = Gram + (size_t)b*1048576;
  const int bm = i*128, bn = j*128;

  __shared__ __align__(16) bf16 sAB[16384];  // 32 KiB: sA|sB, reused as transpose buf
  bf16* sA = sAB; bf16* sB = sAB + 8192;
  const int t = threadIdx.x, w = t>>6, l = t&63;
  const int wr = (w>>1)*64, wc = (w&1)*64;
  f32x4 acc[4][4] = {};
  const int srow = l>>3;
  const int scol = ((l&7) ^ (l>>3))*8;
  for (int kt=0; kt<64; ++kt) {
    const int k0 = kt*64;
    #pragma unroll
    for (int ii=0;ii<4;++ii){
      int c = w*4+ii;
      int row = c*8 + srow;
      gload_lds16(A + (size_t)(bm+row)*4096 + k0 + scol, (char*)sA + c*1024);
      gload_lds16(A + (size_t)(bn+row)*4096 + k0 + scol, (char*)sB + c*1024);
    }
    __syncthreads();
    #pragma unroll
    for (int kk=0; kk<64; kk+=32) {
      bf16x8 af[4], bfr[4];
      const int xr = ((kk + 8*(l>>4))*2) ^ ((l&7)<<4);
      #pragma unroll
      for (int mf=0;mf<4;++mf)
        af[mf] = *(const bf16x8*)((const char*)sA + (wr+mf*16+(l&15))*128 + xr);
      #pragma unroll
      for (int nf=0;nf<4;++nf)
        bfr[nf] = *(const bf16x8*)((const char*)sB + (wc+nf*16+(l&15))*128 + xr);
      #pragma unroll
      for (int mf=0;mf<4;++mf)
        #pragma unroll
        for (int nf=0;nf<4;++nf)
          acc[mf][nf] = __builtin_amdgcn_mfma_f32_16x16x32_bf16(af[mf], bfr[nf], acc[mf][nf], 0,0,0);
    }
    __syncthreads();
  }
  // normal write: C[bm+row][bn+col]
  #pragma unroll
  for (int mf=0;mf<4;++mf)
    #pragma unroll
    for (int nf=0;nf<4;++nf)
      #pragma unroll
      for (int r=0;r<4;++r){
        int row = bm + wr + mf*16 + (l>>4)*4 + r;
        int col = bn + wc + nf*16 + (l&15);
        C[(size_t)row*1024 + col] = (bf16)acc[mf][nf][r];
      }
  if (i == j) return;
  // mirror write: C[bn+col][bm+row] via LDS transpose, two 64-col halves.
  // tr layout: [64 cols][136 rows-padded] bf16 (272B stride, 16B aligned).
  for (int h2=0; h2<2; ++h2){
    __syncthreads();
    if ((w&1) == h2){
      #pragma unroll
      for (int mf=0;mf<4;++mf)
        #pragma unroll
        for (int nf=0;nf<4;++nf)
          #pragma unroll
          for (int p=0;p<2;++p){
            int col_local = nf*16 + (l&15);
            int rowb = wr + mf*16 + (l>>4)*4 + 2*p;
            *(uint32_t*)((char*)sAB + (col_local*136 + rowb)*2) =
              packbf2(acc[mf][nf][2*p], acc[mf][nf][2*p+1]);
          }
    }
    __syncthreads();
    {
      int col_local = t>>2, sub = t&3;
      const uint4* src = (const uint4*)((const char*)sAB + col_local*272 + sub*64);
      uint4 v0 = src[0], v1 = src[1], v2 = src[2], v3 = src[3];
      bf16* dst = C + (size_t)(bn + h2*64 + col_local)*1024 + bm + sub*32;
      ((uint4*)dst)[0]=v0; ((uint4*)dst)[1]=v1; ((uint4*)dst)[2]=v2; ((uint4*)dst)[3]=v3;
    }
  }
}

// =====================================================================
// 256x256-tile pipelined GEMM (r3 structure), fused epilogue:
// C = bf16(A*BT^T + bias + resid), resid bf16, batched via z.
// =====================================================================
__global__ __launch_bounds__(512, 2) void k_gemm256(
    const bf16* __restrict__ A, const bf16* __restrict__ BT, bf16* __restrict__ C,
    int N, int K,
    const float* __restrict__ bias, const bf16* __restrict__ resid,
    size_t As, size_t Bs, size_t Cs, size_t Rs)
{
  A += blockIdx.z*As; BT += blockIdx.z*Bs; C += blockIdx.z*Cs; resid += blockIdx.z*Rs;
  __shared__ __align__(16) bf16 lds[2][2][256*64];
  bf16* bA0 = &lds[0][0][0]; bf16* bB0 = &lds[0][1][0];
  bf16* bA1 = &lds[1][0][0]; bf16* bB1 = &lds[1][1][0];

  const int t = threadIdx.x, w = t>>6, l = t&63;
  const int wm = w>>2, wn = w&3;

  const int nwg = gridDim.x * gridDim.y;
  const int orig = blockIdx.y * gridDim.x + blockIdx.x;
  const int q = nwg >> 3, r = nwg & 7;
  const int xcd = orig & 7, loc = orig >> 3;
  const int swz = (xcd < r ? xcd*(q+1) : r*(q+1) + (xcd-r)*q) + loc;
  const int bx = swz % gridDim.x, by = swz / gridDim.x;
  const int bm = by*256, bn = bx*256;

  const int co0 = (16*(l>>4)) ^ ((l&7)<<4);
  const int co1 = (64 + 16*(l>>4)) ^ ((l&7)<<4);

  auto stageA = [&](const bf16* G, bf16* Ldst, int j, int k0){
    int row = wm*128 + wn*32 + j*8 + (l>>3);
    int col = 8*((l&7) ^ (l>>3));
    gload_lds16(G + (size_t)(bm + row)*K + k0 + col,
                Ldst + (wm*128 + wn*32 + j*8)*64);
  };
  auto stageB = [&](const bf16* G, bf16* Ldst, int j, int k0){
    int row = j*64 + w*8 + (l>>3);
    int col = 8*((l&7) ^ (l>>3));
    gload_lds16(G + (size_t)(bn + row)*K + k0 + col,
                Ldst + (j*64 + w*8)*64);
  };

#define RD_AA(dst, qd, base) {                                                  \
    const int r0 = wm*128 + (qd)*32 + (l&15);                                   \
    dst[0][0] = *(const bf16x8*)((const char*)(base) + (r0   )*128 + co0);      \
    dst[0][1] = *(const bf16x8*)((const char*)(base) + (r0   )*128 + co1);      \
    dst[1][0] = *(const bf16x8*)((const char*)(base) + (r0+16)*128 + co0);      \
    dst[1][1] = *(const bf16x8*)((const char*)(base) + (r0+16)*128 + co1);      \
  }

#define MFMA_Q(P, AA) {                                                         \
    __builtin_amdgcn_s_setprio(1);                                              \
    _Pragma("unroll")                                                           \
    for (int kk=0;kk<2;++kk)                                                    \
      _Pragma("unroll")                                                         \
      for (int i=0;i<2;++i)                                                     \
        _Pragma("unroll")                                                       \
        for (int nf=0;nf<4;++nf)                                                \
          acc[2*(P)+i][nf] = __builtin_amdgcn_mfma_f32_16x16x32_bf16(           \
              AA[i][kk], bfr[nf][kk], acc[2*(P)+i][nf], 0,0,0);                 \
    __builtin_amdgcn_s_setprio(0);                                              \
  }

#define BAR asm volatile("s_barrier" ::: "memory")

  f32x4 acc[8][4] = {};
  const int NT = K >> 6;

  #pragma unroll
  for (int j=0;j<4;++j) stageA(A, bA0, j, 0);
  #pragma unroll
  for (int j=0;j<4;++j) stageB(BT, bB0, j, 0);
  __builtin_amdgcn_sched_barrier(0);
  if (NT > 1){
    #pragma unroll
    for (int j=0;j<4;++j) stageB(BT, bB1, j, 64);
    asm volatile("s_waitcnt vmcnt(4)" ::: "memory");
  } else {
    asm volatile("s_waitcnt vmcnt(0)" ::: "memory");
  }
  BAR;

  bf16x8 aaA[2][2], aaB[2][2];
  RD_AA(aaA, wn, bA0);

  for (int T = 0; T < NT; ++T){
    bf16* sA  = (T&1) ? bA1 : bA0;
    bf16* sB  = (T&1) ? bB1 : bB0;
    bf16* sAn = (T&1) ? bA0 : bA1;
    const int kA = (T+1)<<6, kB = (T+2)<<6;
    const bool stA = (T+1) < NT, stB = (T+2) < NT;

    bf16x8 bfr[4][2];
    const int rb = wn*64 + (l&15);
    #pragma unroll
    for (int nf=0;nf<4;++nf){
      bfr[nf][0] = *(const bf16x8*)((const char*)sB + (rb+nf*16)*128 + co0);
      bfr[nf][1] = *(const bf16x8*)((const char*)sB + (rb+nf*16)*128 + co1);
    }

    RD_AA(aaB, (wn+1)&3, sA);
    if (stA){ stageA(A, sAn, 0, kA); stageA(A, sAn, 1, kA); }
    BAR; MFMA_Q(0, aaA); BAR;

    RD_AA(aaA, (wn+2)&3, sA);
    if (stA){ stageA(A, sAn, 2, kA); stageA(A, sAn, 3, kA); }
    BAR; MFMA_Q(1, aaB); BAR;

    RD_AA(aaB, (wn+3)&3, sA);
    if (stB){ stageB(BT, sB, 0, kB); stageB(BT, sB, 1, kB); }
    BAR; MFMA_Q(2, aaA); BAR;

    if (stB){
      stageB(BT, sB, 2, kB); stageB(BT, sB, 3, kB);
      asm volatile("s_waitcnt vmcnt(4)" ::: "memory");
    } else {
      asm volatile("s_waitcnt vmcnt(0)" ::: "memory");
    }
    if (stA) RD_AA(aaA, wn, sAn);
    BAR; MFMA_Q(3, aaB); BAR;
  }
#undef RD_AA
#undef MFMA_Q
#undef BAR

  #pragma unroll
  for (int P=0; P<4; ++P){
    const int qd = (P+wn)&3;
    #pragma unroll
    for (int i=0;i<2;++i){
      #pragma unroll
      for (int nf=0; nf<4; ++nf){
        #pragma unroll
        for (int r2=0; r2<4; ++r2){
          int row = bm + wm*128 + qd*32 + i*16 + (l>>4)*4 + r2;
          int col = bn + wn*64 + nf*16 + (l&15);
          float v = acc[2*P+i][nf][r2] + bias[col] + (float)resid[(size_t)row*N + col];
          C[(size_t)row*N + col] = (bf16)v;
        }
      }
    }
  }
}

// ---------- fused S = scale * T2_g @ Wv_g^T + row softmax -> Aatt[bg][64][64] ----------
__global__ __launch_bounds__(256) void k_sgemm64(const bf16* __restrict__ T2, const bf16* __restrict__ WqkvT,
                                                 bf16* __restrict__ Aatt){
  const int bg = blockIdx.x, b = bg>>4, g = bg&15;
  const bf16* Arows = T2 + (size_t)b*1048576 + (size_t)(g*64)*1024;
  const bf16* Brows = WqkvT + (size_t)(2048 + g*64)*1024;
  __shared__ __align__(16) bf16 sA[64*64];
  __shared__ __align__(16) bf16 sB[64*64];
  const int t = threadIdx.x, w = t>>6, l = t&63;
  const int srow = l>>3, scol = ((l&7)^(l>>3))*8;
  f32x4 acc[4] = {};
  for (int kt=0; kt<16; ++kt){
    const int k0 = kt*64;
    gload_lds16(Arows + (size_t)(w*8+srow)*1024 + k0 + scol,      sA + (w*8)*64);
    gload_lds16(Arows + (size_t)(32+w*8+srow)*1024 + k0 + scol,   sA + (32+w*8)*64);
    gload_lds16(Brows + (size_t)(w*8+srow)*1024 + k0 + scol,      sB + (w*8)*64);
    gload_lds16(Brows + (size_t)(32+w*8+srow)*1024 + k0 + scol,   sB + (32+w*8)*64);
    __syncthreads();
    #pragma unroll
    for (int kk=0; kk<64; kk+=32){
      const int xr = ((kk + 8*(l>>4))*2) ^ ((l&7)<<4);
      bf16x8 af = *(const bf16x8*)((const char*)sA + (w*16+(l&15))*128 + xr);
      #pragma unroll
      for (int nf=0; nf<4; ++nf){
        bf16x8 bfv = *(const bf16x8*)((const char*)sB + (nf*16+(l&15))*128 + xr);
        acc[nf] = __builtin_amdgcn_mfma_f32_16x16x32_bf16(af, bfv, acc[nf], 0,0,0);
      }
    }
    __syncthreads();
  }
  #pragma unroll
  for (int reg=0; reg<4; ++reg){
    float m = -3.4e38f;
    #pragma unroll
    for (int nf=0; nf<4; ++nf) m = fmaxf(m, acc[nf][reg]);
    m = fmaxf(m, __shfl_xor(m,1)); m = fmaxf(m, __shfl_xor(m,2));
    m = fmaxf(m, __shfl_xor(m,4)); m = fmaxf(m, __shfl_xor(m,8));
    float e[4]; float s = 0.f;
    #pragma unroll
    for (int nf=0; nf<4; ++nf){ e[nf] = __expf((acc[nf][reg]-m)*0.125f); s += e[nf]; }
    s += __shfl_xor(s,1); s += __shfl_xor(s,2); s += __shfl_xor(s,4); s += __shfl_xor(s,8);
    const float inv = 1.0f/s;
    const int row = w*16 + (l>>4)*4 + reg;
    #pragma unroll
    for (int nf=0; nf<4; ++nf)
      Aatt[(size_t)bg*4096 + row*64 + nf*16 + (l&15)] = (bf16)(e[nf]*inv);
  }
}

// ---------- U[c][g*64+d] = sum_e Wq[c][g*64+e] * Aatt_bg[d][e] ----------
__global__ __launch_bounds__(256) void k_applyW(const bf16* __restrict__ Wqkvb, const bf16* __restrict__ Aatt,
                                                bf16* __restrict__ U){
  const int bg = blockIdx.y, b = bg>>4, g = bg&15;
  const int m0 = blockIdx.x*128;
  __shared__ __align__(16) bf16 Pl[64][72];
  const int t = threadIdx.x, w = t>>6, l = t&63;
  for (int idx=t; idx<1024; idx+=256){
    int r2 = idx>>4, c4 = (idx&15)*4;
    *(uint2*)&Pl[r2][c4] = *(const uint2*)&Aatt[(size_t)bg*4096 + r2*64 + c4];
  }
  __syncthreads();
  f32x4 acc[2][4] = {};
  const bf16* Ab = Wqkvb + (size_t)(m0 + w*32)*3072 + g*64;
  #pragma unroll
  for (int kk=0; kk<64; kk+=32){
    bf16x8 af[2], pf[4];
    #pragma unroll
    for (int mf=0;mf<2;++mf)
      af[mf] = *(const bf16x8*)(Ab + (size_t)(mf*16 + (l&15))*3072 + kk + 8*(l>>4));
    #pragma unroll
    for (int nf=0;nf<4;++nf)
      pf[nf] = *(const bf16x8*)&Pl[nf*16 + (l&15)][kk + 8*(l>>4)];
    #pragma unroll
    for (int mf=0;mf<2;++mf)
      #pragma unroll
      for (int nf=0;nf<4;++nf)
        acc[mf][nf] = __builtin_amdgcn_mfma_f32_16x16x32_bf16(af[mf], pf[nf], acc[mf][nf], 0,0,0);
  }
  #pragma unroll
  for (int mf=0;mf<2;++mf)
    #pragma unroll
    for (int nf=0;nf<4;++nf)
      #pragma unroll
      for (int r=0;r<4;++r){
        int rowc = m0 + w*32 + mf*16 + (l>>4)*4 + r;
        int col = g*64 + nf*16 + (l&15);
        U[(size_t)b*1048576 + (size_t)rowc*1024 + col] = (bf16)acc[mf][nf][r];
      }
}

// ---------- LayerNorm: wave per row of 1024 ----------
__global__ __launch_bounds__(256) void k_ln(const bf16* __restrict__ h, const float* __restrict__ gamma,
                                            const float* __restrict__ beta, float* __restrict__ y){
  const int w = threadIdx.x>>6, l = threadIdx.x&63;
  const size_t row = (size_t)blockIdx.x*4 + w;
  const bf16* hr = h + row*1024 + l*16;
  uint4 p0 = *(const uint4*)hr;
  uint4 p1 = *(const uint4*)(hr+8);
  float v[16];
  const uint32_t* pw = (const uint32_t*)&p0;
  #pragma unroll
  for (int i=0;i<4;++i){ v[2*i] = bits2f(pw[i]<<16); v[2*i+1] = bits2f(pw[i]&0xffff0000u); }
  const uint32_t* pw1 = (const uint32_t*)&p1;
  #pragma unroll
  for (int i=0;i<4;++i){ v[8+2*i] = bits2f(pw1[i]<<16); v[8+2*i+1] = bits2f(pw1[i]&0xffff0000u); }
  float s=0.f, s2=0.f;
  #pragma unroll
  for (int i=0;i<16;++i){ s+=v[i]; s2+=v[i]*v[i]; }
  #pragma unroll
  for (int off=1; off<64; off<<=1){ s += __shfl_xor(s,off); s2 += __shfl_xor(s2,off); }
  float mu = s*(1.0f/1024.0f);
  float var = s2*(1.0f/1024.0f) - mu*mu;
  float rinv = rsqrtf(var + 1e-5f);
  const float* gp = gamma + l*16; const float* bp = beta + l*16;
  float o[16];
  #pragma unroll
  for (int i=0;i<16;++i) o[i] = gp[i]*(v[i]-mu)*rinv + bp[i];
  float* yr = y + row*1024 + l*16;
  #pragma unroll
  for (int i=0;i<4;++i) ((float4*)yr)[i] = *(float4*)&o[4*i];
}

extern "C" void kernel_launch(void* const* d_in, const int* in_sizes, int n_in,
                              void* d_out, int out_size, void* d_ws, size_t ws_size,
                              hipStream_t stream){
  const float* x     = (const float*)d_in[0];
  const float* Wqkv  = (const float*)d_in[1];
  const float* Wproj = (const float*)d_in[2];
  const float* bproj = (const float*)d_in[3];
  const float* gamma = (const float*)d_in[4];
  const float* beta  = (const float*)d_in[5];
  float* y = (float*)d_out;

  char* ws = (char*)d_ws;
  size_t off = 0;
  auto alloc = [&](size_t bytes)->void*{ void* p = ws + off; off += (bytes + 255) & ~(size_t)255; return p; };
  bf16* xb     = (bf16*)alloc((size_t)32768*1024*2);   // 67.1 MB
  bf16* xT     = (bf16*)alloc((size_t)8*1024*4096*2);  // 67.1 MB (reused as h)
  bf16* Wqkvb  = (bf16*)alloc((size_t)1024*3072*2);
  bf16* WqkvT  = (bf16*)alloc((size_t)3072*1024*2);
  bf16* WprojT = (bf16*)alloc((size_t)1024*1024*2);
  bf16* Gram   = (bf16*)alloc((size_t)8*1024*1024*2);  // 16.8 MB
  bf16* T2     = (bf16*)alloc((size_t)8*1024*1024*2);
  bf16* Aatt   = (bf16*)alloc((size_t)128*64*64*2);
  bf16* U      = (bf16*)alloc((size_t)8*1024*1024*2);
  bf16* WeffT  = (bf16*)alloc((size_t)8*1024*1024*2);
  bf16* h      = xT;   // xT dead after Gram

  const size_t MB1 = 1048576;

  k_castT<<<dim3(16,64,8),256,0,stream>>>(x, xb, xT);
  k_cast<<<1536,256,0,stream>>>(Wqkv, Wqkvb, 3145728);
  k_transpose<<<dim3(96,32),256,0,stream>>>(Wqkv, WqkvT, 1024, 3072);
  k_transpose<<<dim3(32,32),256,0,stream>>>(Wproj, WprojT, 1024, 1024);
  // Gram_b = xT_b @ xT_b^T (symmetric, upper tiles + mirror, XCD-chunked)
  k_gramsym<<<dim3(36,8),256,0,stream>>>(xT, Gram);
  // T2_b = Wk^T @ Gram_b  [1024x1024], K=1024  (Gram symmetric)
  k_gemm128<<<dim3(8,8,8),256,0,stream>>>(WqkvT + (size_t)1024*1024, Gram, T2, 1024, 1024, 1024, 1024,
                                          0, MB1, MB1);
  // S + softmax -> Aatt
  k_sgemm64<<<128,256,0,stream>>>(T2, WqkvT, Aatt);
  // U_b[:, g-block] = Wq_g @ Aatt_bg^T
  k_applyW<<<dim3(8,128),256,0,stream>>>(Wqkvb, Aatt, U);
  // WeffT_b = WprojT @ U_b^T  [1024x1024], K=1024
  k_gemm128<<<dim3(8,8,8),256,0,stream>>>(WprojT, U, WeffT, 1024, 1024, 1024, 1024,
                                          0, MB1, MB1);
  // h_b = xb_b @ WeffT_b^T + bproj + xb_b   [4096x1024] per batch
  k_gemm256<<<dim3(4,16,8),512,0,stream>>>(xb, WeffT, h, 1024, 1024, bproj, xb,
                                           (size_t)4096*1024, MB1, (size_t)4096*1024, (size_t)4096*1024);
  k_ln<<<8192,256,0,stream>>>(h, gamma, beta, y);
}